// Round 5
// baseline (308.117 us; speedup 1.0000x reference)
//
#include <hip/hip_runtime.h>
#include <math.h>

#define NPIX 4096
#define CCH  128

typedef __attribute__((ext_vector_type(8))) short  bf8;   // 8 bf16 in 4 VGPRs
typedef __attribute__((ext_vector_type(4))) float  f4;

#define MFMA(a, b, c) __builtin_amdgcn_mfma_f32_16x16x32_bf16(a, b, c, 0, 0, 0)

__device__ __forceinline__ unsigned short f2bf(float x) {
    union { float f; unsigned u; } v; v.f = x;
    unsigned r = v.u + 0x7fffu + ((v.u >> 16) & 1u);   // RNE
    return (unsigned short)(r >> 16);
}
__device__ __forceinline__ float bf2f(unsigned short h) {
    union { float f; unsigned u; } v; v.u = ((unsigned)h) << 16;
    return v.f;
}
// pack two floats to bf16x2 (lo in low short), half-ulp round, 3 VALU ops
__device__ __forceinline__ unsigned pk2r(float lo, float hi) {
    union { float f; unsigned u; } a, b; a.f = hi; b.f = lo;
    return __builtin_amdgcn_perm(a.u + 0x8000u, b.u + 0x8000u, 0x07060302u);
}

// Workspace layout (bytes), total exactly 32 MB:
//   xn   0..4M     bf16 [pix 16384][c 128]  (dead after qkv_kernel)
//   lbuf 0..1M     fp32 4 slices [bh][n]    (overlays xn, written by flash)
//   qh   4..8M     bf16 [bh][n][32]  (pre-scaled by 32^-.5 * log2e)
//   kh   8..12M    bf16 [bh][n][32]
//   vth  12..16M   bf16 [bh*32+d][n]
//   aob  16..32M   bf16 4 slices [bh*32+d][n]  (unnormalized O partials)

// ---------------------------------------------------------------------------
// Kernel 1: LayerNorm -> xn bf16 [pix][c]. grid 1024 x 256 thr (16 pix/block).
// ---------------------------------------------------------------------------
__global__ __launch_bounds__(256) void ln_kernel(
    const float* __restrict__ x, const float* __restrict__ g,
    const float* __restrict__ bvec, unsigned short* __restrict__ xn)
{
    const int blk = blockIdx.x;
    const int b  = blk >> 8;
    const int n0 = (blk & 255) << 4;
    const int t  = threadIdx.x;

    __shared__ float xs[CCH * 17];     // [c][pix], stride 17
    __shared__ float red0[16][16];
    __shared__ float red1[16][16];
    __shared__ float mean_s[16];
    __shared__ float rstd_s[16];

    const float* xb = x + (size_t)b * CCH * NPIX + n0;
#pragma unroll
    for (int k = 0; k < 8; ++k) {
        int e = k * 256 + t;
        int c = e >> 4, p = e & 15;
        xs[c * 17 + p] = xb[(size_t)c * NPIX + p];
    }
    __syncthreads();

    {
        int pix = t & 15, cg = t >> 4;
        float s = 0.f, s2 = 0.f;
#pragma unroll
        for (int cc = 0; cc < 8; ++cc) {
            float v = xs[(cg * 8 + cc) * 17 + pix];
            s += v; s2 += v * v;
        }
        red0[cg][pix] = s; red1[cg][pix] = s2;
    }
    __syncthreads();
    if (t < 16) {
        float s = 0.f, s2 = 0.f;
#pragma unroll
        for (int cg = 0; cg < 16; ++cg) { s += red0[cg][t]; s2 += red1[cg][t]; }
        float mu  = s * (1.f / 128.f);
        float var = s2 * (1.f / 128.f) - mu * mu;
        mean_s[t] = mu;
        rstd_s[t] = rsqrtf(var + 1e-5f);
    }
    __syncthreads();

    // normalize + pack: thread -> (pix = t>>4, c0 = (t&15)*8)
    const int pix = t >> 4;
    const int c0  = (t & 15) * 8;
    const float mu = mean_s[pix], rs = rstd_s[pix];
    unsigned ow[4];
#pragma unroll
    for (int i = 0; i < 4; ++i) {
        int c = c0 + 2 * i;
        float f0 = (xs[c * 17 + pix]       - mu) * rs * g[c]     + bvec[c];
        float f1 = (xs[(c + 1) * 17 + pix] - mu) * rs * g[c + 1] + bvec[c + 1];
        ow[i] = pk2r(f0, f1);
    }
    unsigned short* dst = xn + (size_t)(b * NPIX + n0 + pix) * CCH + c0;
    *(uint4*)dst = *(uint4*)ow;
}

// ---------------------------------------------------------------------------
// Kernel 2: QKV projection as MFMA GEMM (unchanged structure).
// grid (64 pixgroups, 24 o-tiles) x 256 thr.
// ---------------------------------------------------------------------------
__global__ __launch_bounds__(256) void qkv_kernel(
    const float* __restrict__ w_qkv, const unsigned short* __restrict__ xn,
    unsigned short* __restrict__ qh, unsigned short* __restrict__ kh,
    unsigned short* __restrict__ vth)
{
    const int pg = blockIdx.x;          // 0..63
    const int ot = blockIdx.y;          // 0..23 (0-7 q, 8-15 k, 16-23 v)
    const int t  = threadIdx.x;
    const int wv = t >> 6;
    const int l16 = t & 15;
    const int quad = (t & 63) >> 4;
    const int pix0 = pg * 256 + wv * 64;
    const int b = pg >> 4;

    __shared__ unsigned lds_t[4][64][8];

    const float qs2 = 0.17677669529663687f * 1.4426950408889634f;
    const float ascale = (ot < 8) ? qs2 : 1.0f;
    const float* wrow = w_qkv + (size_t)(ot * 16 + l16) * CCH;
    bf8 aw[4];
#pragma unroll
    for (int kk = 0; kk < 4; ++kk) {
        float wb[8];
        *(float4*)&wb[0] = *(const float4*)&wrow[kk * 32 + quad * 8];
        *(float4*)&wb[4] = *(const float4*)&wrow[kk * 32 + quad * 8 + 4];
#pragma unroll
        for (int j = 0; j < 8; ++j) aw[kk][j] = (short)f2bf(wb[j] * ascale);
    }

    const f4 z = {0.f, 0.f, 0.f, 0.f};
    f4 acc[4] = {z, z, z, z};
#pragma unroll
    for (int s = 0; s < 4; ++s) {
        const unsigned short* xrow = xn + (size_t)(pix0 + s * 16 + l16) * CCH;
#pragma unroll
        for (int kk = 0; kk < 4; ++kk) {
            const bf8 bx = *(const bf8*)&xrow[kk * 32 + quad * 8];
            acc[s] = MFMA(aw[kk], bx, acc[s]);
        }
    }

    if (ot < 16) {
#pragma unroll
        for (int s = 0; s < 4; ++s) {
            uint2 wp;
            wp.x = pk2r(acc[s].x, acc[s].y);
            wp.y = pk2r(acc[s].z, acc[s].w);
            *(uint2*)&lds_t[wv][s * 16 + l16][quad * 2] = wp;
        }
        const int L = t & 63;
        const uint4 r0 = *(const uint4*)&lds_t[wv][L][0];
        const uint4 r1 = *(const uint4*)&lds_t[wv][L][4];
        const int n  = (pix0 + L) & (NPIX - 1);
        const int h  = (ot & 7) >> 1;
        const int d0 = (ot & 1) * 16;
        const int bh = b * 4 + h;
        unsigned short* dst = ((ot < 8) ? qh : kh)
                            + ((size_t)bh * NPIX + n) * 32 + d0;
        *(uint4*)&dst[0] = r0;
        *(uint4*)&dst[8] = r1;
    } else {
        const int ov = (ot - 16) * 16;
        const int bh = b * 4 + (ov >> 5);
        const int dvb = (ov & 31) + quad * 4;
#pragma unroll
        for (int s = 0; s < 4; ++s) {
            const int n = (pix0 + s * 16 + l16) & (NPIX - 1);
#pragma unroll
            for (int r = 0; r < 4; ++r)
                vth[((size_t)bh * 32 + dvb + r) * NPIX + n] = f2bf(acc[s][r]);
        }
    }
}

// ---------------------------------------------------------------------------
// Kernel 3: MFMA flash attention, split-K 4 slices, bf16 O partials.
// 4 waves x 32 q; grid 16bh x 32qt x 4ks = 2048 blocks, XCD-swizzled.
// ---------------------------------------------------------------------------
struct Frags { bf8 k0, k1, v0, v1; };

__device__ __forceinline__ void loadFrags(Frags& f,
    const unsigned short* __restrict__ khb, const unsigned short* __restrict__ vhb,
    int j0, int l16, int quad)
{
    const size_t ka0 = (size_t)(j0 + l16) * 32 + quad * 8;
    f.k0 = *(const bf8*)&khb[ka0];
    f.k1 = *(const bf8*)&khb[ka0 + 16 * 32];
    const size_t va0 = (size_t)l16 * NPIX + j0 + quad * 8;
    f.v0 = *(const bf8*)&vhb[va0];
    f.v1 = *(const bf8*)&vhb[va0 + (size_t)16 * NPIX];
}

__device__ __forceinline__ void tileCompute(const Frags& f,
    const bf8 qA, const bf8 qB, const bf8 ones,
    f4& o00, f4& o10, f4& o01, f4& o11, f4& lA, f4& lB,
    unsigned short (*pbA)[58], unsigned short (*pbB)[58], int l16, int quad)
{
    const f4 z = {0.f, 0.f, 0.f, 0.f};
    f4 sA0 = MFMA(f.k0, qA, z);
    f4 sA1 = MFMA(f.k1, qA, z);
    f4 sB0 = MFMA(f.k0, qB, z);
    f4 sB1 = MFMA(f.k1, qB, z);

    float pA0 = __builtin_amdgcn_exp2f(sA0.x), pA1 = __builtin_amdgcn_exp2f(sA0.y);
    float pA2 = __builtin_amdgcn_exp2f(sA0.z), pA3 = __builtin_amdgcn_exp2f(sA0.w);
    float pA4 = __builtin_amdgcn_exp2f(sA1.x), pA5 = __builtin_amdgcn_exp2f(sA1.y);
    float pA6 = __builtin_amdgcn_exp2f(sA1.z), pA7 = __builtin_amdgcn_exp2f(sA1.w);
    float pB0 = __builtin_amdgcn_exp2f(sB0.x), pB1 = __builtin_amdgcn_exp2f(sB0.y);
    float pB2 = __builtin_amdgcn_exp2f(sB0.z), pB3 = __builtin_amdgcn_exp2f(sB0.w);
    float pB4 = __builtin_amdgcn_exp2f(sB1.x), pB5 = __builtin_amdgcn_exp2f(sB1.y);
    float pB6 = __builtin_amdgcn_exp2f(sB1.z), pB7 = __builtin_amdgcn_exp2f(sB1.w);

    // transpose P via wave-private LDS; row stride 58 shorts (29 words, odd)
    // -> all b32 accesses spread banks (gcd(29,32)=1), max 2-way = free.
    unsigned* prA = (unsigned*)&pbA[l16][quad * 4];
    prA[0] = pk2r(pA0, pA1); prA[1] = pk2r(pA2, pA3);
    prA[8] = pk2r(pA4, pA5); prA[9] = pk2r(pA6, pA7);
    unsigned* prB = (unsigned*)&pbB[l16][quad * 4];
    prB[0] = pk2r(pB0, pB1); prB[1] = pk2r(pB2, pB3);
    prB[8] = pk2r(pB4, pB5); prB[9] = pk2r(pB6, pB7);

    union { unsigned u[4]; bf8 v; } ua, ub;
    const unsigned short* ra = &pbA[l16][quad * 8];
    ua.u[0] = *(const unsigned*)&ra[0];
    ua.u[1] = *(const unsigned*)&ra[2];
    ua.u[2] = *(const unsigned*)&ra[4];
    ua.u[3] = *(const unsigned*)&ra[6];
    const unsigned short* rb = &pbB[l16][quad * 8];
    ub.u[0] = *(const unsigned*)&rb[0];
    ub.u[1] = *(const unsigned*)&rb[2];
    ub.u[2] = *(const unsigned*)&rb[4];
    ub.u[3] = *(const unsigned*)&rb[6];

    o00 = MFMA(f.v0, ua.v, o00); o10 = MFMA(f.v1, ua.v, o10);
    o01 = MFMA(f.v0, ub.v, o01); o11 = MFMA(f.v1, ub.v, o11);
    lA  = MFMA(ones, ua.v, lA);  lB  = MFMA(ones, ub.v, lB);
}

__global__ __launch_bounds__(256, 8) void flash_kernel(
    const unsigned short* __restrict__ qh, const unsigned short* __restrict__ kh,
    const unsigned short* __restrict__ vth,
    unsigned short* __restrict__ aob, float* __restrict__ lbuf)
{
    const int blk = blockIdx.x;
    const int bh  = (blk & 7) + 8 * ((blk >> 3) & 1);   // XCD-local per bh
    const int rem = blk >> 4;
    const int qt  = rem & 31;
    const int ks  = rem >> 5;                            // 0..3
    const int t   = threadIdx.x;
    const int wv  = t >> 6;
    const int l16 = t & 15;
    const int quad = (t & 63) >> 4;
    const int q0  = qt * 128 + wv * 32;

    __shared__ unsigned short pbuf_raw[4][2][16][58];   // 14.5 KB
    unsigned short (*pbA)[58] = pbuf_raw[wv][0];
    unsigned short (*pbB)[58] = pbuf_raw[wv][1];

    const size_t qbaseA = ((size_t)bh * NPIX + q0 + l16) * 32 + quad * 8;
    const bf8 qA = *(const bf8*)&qh[qbaseA];
    const bf8 qB = *(const bf8*)&qh[qbaseA + 16 * 32];

    const unsigned short* khb = kh  + (size_t)bh * NPIX * 32;
    const unsigned short* vhb = vth + (size_t)bh * 32 * NPIX;

    const short one = (short)0x3f80;
    const bf8 ones = {one, one, one, one, one, one, one, one};

    const f4 z = {0.f, 0.f, 0.f, 0.f};
    f4 o00 = z, o10 = z, o01 = z, o11 = z, lA = z, lB = z;

    const int jbase = ks * 1024;
    Frags fa, fb;
    loadFrags(fa, khb, vhb, jbase, l16, quad);
    for (int jt = 0; jt < 32; jt += 2) {
        loadFrags(fb, khb, vhb, jbase + (jt + 1) * 32, l16, quad);
        tileCompute(fa, qA, qB, ones, o00, o10, o01, o11, lA, lB, pbA, pbB, l16, quad);
        loadFrags(fa, khb, vhb, jbase + (jt + 2) * 32, l16, quad);  // tail over-read stays in ws
        tileCompute(fb, qA, qB, ones, o00, o10, o01, o11, lA, lB, pbA, pbB, l16, quad);
    }

    // epilogue: bf16 partial-O stores into this ks-slice
    unsigned short* aos = aob + (size_t)ks * 2097152;
    unsigned short* aoA = aos + (size_t)bh * 32 * NPIX + q0 + l16;
    unsigned short* aoB = aoA + 16;
#pragma unroll
    for (int r = 0; r < 4; ++r) {
        aoA[(size_t)(quad * 4 + r) * NPIX]      = f2bf(o00[r]);
        aoA[(size_t)(16 + quad * 4 + r) * NPIX] = f2bf(o10[r]);
        aoB[(size_t)(quad * 4 + r) * NPIX]      = f2bf(o01[r]);
        aoB[(size_t)(16 + quad * 4 + r) * NPIX] = f2bf(o11[r]);
    }
    if (quad == 0) {
        float* lbs = lbuf + (size_t)ks * 65536;
        lbs[(size_t)bh * NPIX + q0 + l16]      = lA.x;
        lbs[(size_t)bh * NPIX + q0 + 16 + l16] = lB.x;
    }
}

// ---------------------------------------------------------------------------
// Kernel 4: sum 4 O-slices, normalize, MFMA output projection + bias.
// grid (256, 2): block = 64 pix, part = 64-output half.
// ---------------------------------------------------------------------------
__global__ __launch_bounds__(256) void proj_kernel(
    const unsigned short* __restrict__ aob, const float* __restrict__ lbuf,
    const float* __restrict__ w_out, const float* __restrict__ b_out,
    float* __restrict__ out)
{
    const int blk  = blockIdx.x;
    const int part = blockIdx.y;
    const int b  = blk >> 6;
    const int n0 = (blk & 63) << 6;
    const int t  = threadIdx.x;
    const int wv = t >> 6;
    const int l16 = t & 15;
    const int quad = (t & 63) >> 4;

    __shared__ unsigned short xsb[64 * 138];   // [pix][c], stride 138 (odd words)
    __shared__ float linv[4][64];

    {
        int h = t >> 6, p = t & 63;
        size_t li = (size_t)(b * 4 + h) * NPIX + n0 + p;
        linv[h][p] = 1.0f / (lbuf[li] + lbuf[li + 65536]
                           + lbuf[li + 131072] + lbuf[li + 196608]);
    }
    __syncthreads();

    const size_t base = (size_t)(b * CCH) * NPIX + n0;
#pragma unroll
    for (int k = 0; k < 32; ++k) {
        int e = k * 256 + t;
        int c = e >> 6, p = e & 63;
        size_t idx = base + (size_t)c * NPIX + p;
        float s = bf2f(aob[idx])           + bf2f(aob[idx + 2097152])
                + bf2f(aob[idx + 4194304]) + bf2f(aob[idx + 6291456]);
        xsb[p * 138 + c] = f2bf(s * linv[c >> 5][p]);
    }
    __syncthreads();

    // A-frags: w_out rows (o = o0 + l16)
    const int o0 = part * 64 + wv * 16;
    const float* wrow = w_out + (size_t)(o0 + l16) * CCH;
    bf8 aw[4];
#pragma unroll
    for (int kk = 0; kk < 4; ++kk) {
        float wb[8];
        *(float4*)&wb[0] = *(const float4*)&wrow[kk * 32 + quad * 8];
        *(float4*)&wb[4] = *(const float4*)&wrow[kk * 32 + quad * 8 + 4];
#pragma unroll
        for (int j = 0; j < 8; ++j) aw[kk][j] = (short)f2bf(wb[j]);
    }

    const f4 z = {0.f, 0.f, 0.f, 0.f};
    f4 acc[4] = {z, z, z, z};
#pragma unroll
    for (int s = 0; s < 4; ++s) {
#pragma unroll
        for (int kk = 0; kk < 4; ++kk) {
            const unsigned short* row = &xsb[(s * 16 + l16) * 138 + kk * 32 + quad * 8];
            union { unsigned u[4]; bf8 v; } pb;
            pb.u[0] = *(const unsigned*)&row[0];
            pb.u[1] = *(const unsigned*)&row[2];
            pb.u[2] = *(const unsigned*)&row[4];
            pb.u[3] = *(const unsigned*)&row[6];
            acc[s] = MFMA(aw[kk], pb.v, acc[s]);
        }
    }

#pragma unroll
    for (int r = 0; r < 4; ++r) {
        const int o = o0 + quad * 4 + r;
        const float bo = b_out[o];
        float* orow = out + (size_t)(b * CCH + o) * NPIX + n0 + l16;
#pragma unroll
        for (int s = 0; s < 4; ++s)
            orow[s * 16] = acc[s][r] + bo;
    }
}

// ---------------------------------------------------------------------------
extern "C" void kernel_launch(void* const* d_in, const int* in_sizes, int n_in,
                              void* d_out, int out_size, void* d_ws, size_t ws_size,
                              hipStream_t stream) {
    const float* x     = (const float*)d_in[0];
    const float* g     = (const float*)d_in[1];
    const float* bvec  = (const float*)d_in[2];
    const float* w_qkv = (const float*)d_in[3];
    const float* w_out = (const float*)d_in[4];
    const float* b_out = (const float*)d_in[5];
    float* out = (float*)d_out;

    char* ws = (char*)d_ws;
    unsigned short* xn   = (unsigned short*)(ws);           // dead after qkv
    float*          lbuf = (float*)(ws);                    // overlays xn, 1 MB
    unsigned short* qh   = (unsigned short*)(ws + (4u  << 20));
    unsigned short* kh   = (unsigned short*)(ws + (8u  << 20));
    unsigned short* vth  = (unsigned short*)(ws + (12u << 20));
    unsigned short* aob  = (unsigned short*)(ws + (16u << 20)); // 4 slices x 4MB

    ln_kernel   <<<dim3(1024),    dim3(256), 0, stream>>>(x, g, bvec, xn);
    qkv_kernel  <<<dim3(64, 24),  dim3(256), 0, stream>>>(w_qkv, xn, qh, kh, vth);
    flash_kernel<<<dim3(2048),    dim3(256), 0, stream>>>(qh, kh, vth, aob, lbuf);
    proj_kernel <<<dim3(256, 2),  dim3(256), 0, stream>>>(aob, lbuf, w_out, b_out, out);
}

// Round 6
// 193.853 us; speedup vs baseline: 1.5894x; 1.5894x over previous
//
#include <hip/hip_runtime.h>
#include <math.h>

#define NPIX 4096
#define CCH  128

typedef __attribute__((ext_vector_type(8))) short  bf8;   // 8 bf16 in 4 VGPRs
typedef __attribute__((ext_vector_type(4))) float  f4;

#define MFMA(a, b, c) __builtin_amdgcn_mfma_f32_16x16x32_bf16(a, b, c, 0, 0, 0)

__device__ __forceinline__ unsigned short f2bf(float x) {
    union { float f; unsigned u; } v; v.f = x;
    unsigned r = v.u + 0x7fffu + ((v.u >> 16) & 1u);   // RNE
    return (unsigned short)(r >> 16);
}
__device__ __forceinline__ float bf2f(unsigned short h) {
    union { float f; unsigned u; } v; v.u = ((unsigned)h) << 16;
    return v.f;
}
// pack two floats to bf16x2 (lo in low short), half-ulp round, 3 VALU ops
__device__ __forceinline__ unsigned pk2r(float lo, float hi) {
    union { float f; unsigned u; } a, b; a.f = hi; b.f = lo;
    return __builtin_amdgcn_perm(a.u + 0x8000u, b.u + 0x8000u, 0x07060302u);
}

// Workspace layout (bytes), total exactly 32 MB:
//   xn   0..4M     bf16 [pix 16384][c 128]  (dead after qkv_kernel)
//   lbuf 0..512K   fp32 2 slices [bh][n]    (overlays xn, written by flash)
//   qh   4..8M     bf16 [bh][n][32]  (pre-scaled by 32^-.5 * log2e)
//   kh   8..12M    bf16 [bh][n][32]
//   vth  12..16M   bf16 [bh*32+d][n]
//   ao   16..32M   fp32 2 slices [bh*32+d][n]  (unnormalized O partials)

// ---------------------------------------------------------------------------
// Kernel 1: LayerNorm -> xn bf16 [pix][c]. grid 512 x 256 thr (32 pix/block).
// Reads are 128B segments; stats reads conflict-free (stride 33).
// ---------------------------------------------------------------------------
__global__ __launch_bounds__(256) void ln_kernel(
    const float* __restrict__ x, const float* __restrict__ g,
    const float* __restrict__ bvec, unsigned short* __restrict__ xn)
{
    const int blk = blockIdx.x;
    const int b  = blk >> 7;
    const int n0 = (blk & 127) << 5;
    const int t  = threadIdx.x;

    __shared__ float xs[CCH * 33];     // [c][pix], stride 33
    __shared__ float red0[8][32];
    __shared__ float red1[8][32];
    __shared__ float mean_s[32];
    __shared__ float rstd_s[32];

    const float* xb = x + (size_t)b * CCH * NPIX + n0;
#pragma unroll
    for (int k = 0; k < 16; ++k) {
        int e = k * 256 + t;
        int c = e >> 5, p = e & 31;
        xs[c * 33 + p] = xb[(size_t)c * NPIX + p];
    }
    __syncthreads();

    {
        int pix = t & 31, cg = t >> 5;
        float s = 0.f, s2 = 0.f;
#pragma unroll
        for (int cc = 0; cc < 16; ++cc) {
            float v = xs[(cg * 16 + cc) * 33 + pix];
            s += v; s2 += v * v;
        }
        red0[cg][pix] = s; red1[cg][pix] = s2;
    }
    __syncthreads();
    if (t < 32) {
        float s = 0.f, s2 = 0.f;
#pragma unroll
        for (int cg = 0; cg < 8; ++cg) { s += red0[cg][t]; s2 += red1[cg][t]; }
        float mu  = s * (1.f / 128.f);
        float var = s2 * (1.f / 128.f) - mu * mu;
        mean_s[t] = mu;
        rstd_s[t] = rsqrtf(var + 1e-5f);
    }
    __syncthreads();

    // normalize + pack: thread -> (pix = t>>3, c0 = (t&7)*16)
    const int pix = t >> 3;
    const int c0  = (t & 7) * 16;
    const float mu = mean_s[pix], rs = rstd_s[pix];
    unsigned ow[8];
#pragma unroll
    for (int i = 0; i < 8; ++i) {
        int c = c0 + 2 * i;
        float f0 = (xs[c * 33 + pix]       - mu) * rs * g[c]     + bvec[c];
        float f1 = (xs[(c + 1) * 33 + pix] - mu) * rs * g[c + 1] + bvec[c + 1];
        ow[i] = pk2r(f0, f1);
    }
    unsigned short* dst = xn + (size_t)(b * NPIX + n0 + pix) * CCH + c0;
    *(uint4*)&dst[0] = *(uint4*)&ow[0];
    *(uint4*)&dst[8] = *(uint4*)&ow[4];
}

// ---------------------------------------------------------------------------
// Kernel 2: QKV projection as MFMA GEMM (unchanged, proven).
// grid (64 pixgroups, 24 o-tiles) x 256 thr.
// ---------------------------------------------------------------------------
__global__ __launch_bounds__(256) void qkv_kernel(
    const float* __restrict__ w_qkv, const unsigned short* __restrict__ xn,
    unsigned short* __restrict__ qh, unsigned short* __restrict__ kh,
    unsigned short* __restrict__ vth)
{
    const int pg = blockIdx.x;          // 0..63
    const int ot = blockIdx.y;          // 0..23 (0-7 q, 8-15 k, 16-23 v)
    const int t  = threadIdx.x;
    const int wv = t >> 6;
    const int l16 = t & 15;
    const int quad = (t & 63) >> 4;
    const int pix0 = pg * 256 + wv * 64;
    const int b = pg >> 4;

    __shared__ unsigned lds_t[4][64][8];

    const float qs2 = 0.17677669529663687f * 1.4426950408889634f;
    const float ascale = (ot < 8) ? qs2 : 1.0f;
    const float* wrow = w_qkv + (size_t)(ot * 16 + l16) * CCH;
    bf8 aw[4];
#pragma unroll
    for (int kk = 0; kk < 4; ++kk) {
        float wb[8];
        *(float4*)&wb[0] = *(const float4*)&wrow[kk * 32 + quad * 8];
        *(float4*)&wb[4] = *(const float4*)&wrow[kk * 32 + quad * 8 + 4];
#pragma unroll
        for (int j = 0; j < 8; ++j) aw[kk][j] = (short)f2bf(wb[j] * ascale);
    }

    const f4 z = {0.f, 0.f, 0.f, 0.f};
    f4 acc[4] = {z, z, z, z};
#pragma unroll
    for (int s = 0; s < 4; ++s) {
        const unsigned short* xrow = xn + (size_t)(pix0 + s * 16 + l16) * CCH;
#pragma unroll
        for (int kk = 0; kk < 4; ++kk) {
            const bf8 bx = *(const bf8*)&xrow[kk * 32 + quad * 8];
            acc[s] = MFMA(aw[kk], bx, acc[s]);
        }
    }

    if (ot < 16) {
#pragma unroll
        for (int s = 0; s < 4; ++s) {
            uint2 wp;
            wp.x = pk2r(acc[s].x, acc[s].y);
            wp.y = pk2r(acc[s].z, acc[s].w);
            *(uint2*)&lds_t[wv][s * 16 + l16][quad * 2] = wp;
        }
        const int L = t & 63;
        const uint4 r0 = *(const uint4*)&lds_t[wv][L][0];
        const uint4 r1 = *(const uint4*)&lds_t[wv][L][4];
        const int n  = (pix0 + L) & (NPIX - 1);
        const int h  = (ot & 7) >> 1;
        const int d0 = (ot & 1) * 16;
        const int bh = b * 4 + h;
        unsigned short* dst = ((ot < 8) ? qh : kh)
                            + ((size_t)bh * NPIX + n) * 32 + d0;
        *(uint4*)&dst[0] = r0;
        *(uint4*)&dst[8] = r1;
    } else {
        const int ov = (ot - 16) * 16;
        const int bh = b * 4 + (ov >> 5);
        const int dvb = (ov & 31) + quad * 4;
#pragma unroll
        for (int s = 0; s < 4; ++s) {
            const int n = (pix0 + s * 16 + l16) & (NPIX - 1);
#pragma unroll
            for (int r = 0; r < 4; ++r)
                vth[((size_t)bh * 32 + dvb + r) * NPIX + n] = f2bf(acc[s][r]);
        }
    }
}

// ---------------------------------------------------------------------------
// Kernel 3: MFMA flash attention — EXACT R4 configuration (measured 101 us):
// split-K 2, fp32 full-line O stores, 4 blocks/CU. grid 1024, XCD-swizzled.
// ---------------------------------------------------------------------------
struct Frags { bf8 k0, k1, v0, v1; };

__device__ __forceinline__ void loadFrags(Frags& f,
    const unsigned short* __restrict__ khb, const unsigned short* __restrict__ vhb,
    int j0, int l16, int quad)
{
    const size_t ka0 = (size_t)(j0 + l16) * 32 + quad * 8;
    f.k0 = *(const bf8*)&khb[ka0];
    f.k1 = *(const bf8*)&khb[ka0 + 16 * 32];
    const size_t va0 = (size_t)l16 * NPIX + j0 + quad * 8;
    f.v0 = *(const bf8*)&vhb[va0];
    f.v1 = *(const bf8*)&vhb[va0 + (size_t)16 * NPIX];
}

__device__ __forceinline__ void tileCompute(const Frags& f,
    const bf8 qA, const bf8 qB, const bf8 ones,
    f4& o00, f4& o10, f4& o01, f4& o11, f4& lA, f4& lB,
    unsigned short (*pbA)[56], unsigned short (*pbB)[56], int l16, int quad)
{
    const f4 z = {0.f, 0.f, 0.f, 0.f};
    f4 sA0 = MFMA(f.k0, qA, z);
    f4 sA1 = MFMA(f.k1, qA, z);
    f4 sB0 = MFMA(f.k0, qB, z);
    f4 sB1 = MFMA(f.k1, qB, z);

    float pA0 = __builtin_amdgcn_exp2f(sA0.x), pA1 = __builtin_amdgcn_exp2f(sA0.y);
    float pA2 = __builtin_amdgcn_exp2f(sA0.z), pA3 = __builtin_amdgcn_exp2f(sA0.w);
    float pA4 = __builtin_amdgcn_exp2f(sA1.x), pA5 = __builtin_amdgcn_exp2f(sA1.y);
    float pA6 = __builtin_amdgcn_exp2f(sA1.z), pA7 = __builtin_amdgcn_exp2f(sA1.w);
    float pB0 = __builtin_amdgcn_exp2f(sB0.x), pB1 = __builtin_amdgcn_exp2f(sB0.y);
    float pB2 = __builtin_amdgcn_exp2f(sB0.z), pB3 = __builtin_amdgcn_exp2f(sB0.w);
    float pB4 = __builtin_amdgcn_exp2f(sB1.x), pB5 = __builtin_amdgcn_exp2f(sB1.y);
    float pB6 = __builtin_amdgcn_exp2f(sB1.z), pB7 = __builtin_amdgcn_exp2f(sB1.w);

    unsigned* prA = (unsigned*)&pbA[l16][quad * 4];
    prA[0] = pk2r(pA0, pA1); prA[1] = pk2r(pA2, pA3);
    prA[8] = pk2r(pA4, pA5); prA[9] = pk2r(pA6, pA7);
    unsigned* prB = (unsigned*)&pbB[l16][quad * 4];
    prB[0] = pk2r(pB0, pB1); prB[1] = pk2r(pB2, pB3);
    prB[8] = pk2r(pB4, pB5); prB[9] = pk2r(pB6, pB7);

    const bf8 pfA = *(const bf8*)&pbA[l16][quad * 8];
    const bf8 pfB = *(const bf8*)&pbB[l16][quad * 8];

    o00 = MFMA(f.v0, pfA, o00); o10 = MFMA(f.v1, pfA, o10);
    o01 = MFMA(f.v0, pfB, o01); o11 = MFMA(f.v1, pfB, o11);
    lA  = MFMA(ones, pfA, lA);  lB  = MFMA(ones, pfB, lB);
}

__global__ __launch_bounds__(256, 4) void flash_kernel(
    const unsigned short* __restrict__ qh, const unsigned short* __restrict__ kh,
    const unsigned short* __restrict__ vth,
    float* __restrict__ ao, float* __restrict__ lbuf)
{
    const int blk = blockIdx.x;
    const int bh  = (blk & 7) + 8 * ((blk >> 3) & 1);   // XCD-local per bh
    const int rem = blk >> 4;
    const int qt  = rem & 31;
    const int ks  = rem >> 5;                            // 0..1
    const int t   = threadIdx.x;
    const int wv  = t >> 6;
    const int l16 = t & 15;
    const int quad = (t & 63) >> 4;
    const int q0  = qt * 128 + wv * 32;

    __shared__ unsigned short pbuf_raw[4][2][16][56];   // 14 KB
    unsigned short (*pbA)[56] = pbuf_raw[wv][0];
    unsigned short (*pbB)[56] = pbuf_raw[wv][1];

    const size_t qbaseA = ((size_t)bh * NPIX + q0 + l16) * 32 + quad * 8;
    const bf8 qA = *(const bf8*)&qh[qbaseA];
    const bf8 qB = *(const bf8*)&qh[qbaseA + 16 * 32];

    const unsigned short* khb = kh  + (size_t)bh * NPIX * 32;
    const unsigned short* vhb = vth + (size_t)bh * 32 * NPIX;

    const short one = (short)0x3f80;
    const bf8 ones = {one, one, one, one, one, one, one, one};

    const f4 z = {0.f, 0.f, 0.f, 0.f};
    f4 o00 = z, o10 = z, o01 = z, o11 = z, lA = z, lB = z;

    const int jbase = ks * 2048;
    Frags fa, fb;
    loadFrags(fa, khb, vhb, jbase, l16, quad);
    for (int jt = 0; jt < 64; jt += 2) {
        loadFrags(fb, khb, vhb, jbase + (jt + 1) * 32, l16, quad);
        tileCompute(fa, qA, qB, ones, o00, o10, o01, o11, lA, lB, pbA, pbB, l16, quad);
        loadFrags(fa, khb, vhb, jbase + (jt + 2) * 32, l16, quad);  // tail over-read stays in ws
        tileCompute(fb, qA, qB, ones, o00, o10, o01, o11, lA, lB, pbA, pbB, l16, quad);
    }

    // epilogue: fp32 stores, full 128B line coverage per wave (A+B adjacent)
    float* aos = ao + (size_t)ks * 2097152;
    float* lbs = lbuf + (size_t)ks * 65536;
    float* aoA = aos + (size_t)bh * 32 * NPIX + q0 + l16;
    float* aoB = aoA + 16;
#pragma unroll
    for (int r = 0; r < 4; ++r) {
        aoA[(size_t)(quad * 4 + r) * NPIX]      = o00[r];
        aoA[(size_t)(16 + quad * 4 + r) * NPIX] = o10[r];
        aoB[(size_t)(quad * 4 + r) * NPIX]      = o01[r];
        aoB[(size_t)(16 + quad * 4 + r) * NPIX] = o11[r];
    }
    if (quad == 0) {
        lbs[(size_t)bh * NPIX + q0 + l16]      = lA.x;
        lbs[(size_t)bh * NPIX + q0 + 16 + l16] = lB.x;
    }
}

// ---------------------------------------------------------------------------
// Kernel 4: sum 2 fp32 O-slices, normalize, MFMA output projection + bias.
// grid (256, 2): block = 64 pix, part = 64-output half.
// ---------------------------------------------------------------------------
__global__ __launch_bounds__(256) void proj_kernel(
    const float* __restrict__ ao, const float* __restrict__ lbuf,
    const float* __restrict__ w_out, const float* __restrict__ b_out,
    float* __restrict__ out)
{
    const int blk  = blockIdx.x;
    const int part = blockIdx.y;
    const int b  = blk >> 6;
    const int n0 = (blk & 63) << 6;
    const int t  = threadIdx.x;
    const int wv = t >> 6;
    const int l16 = t & 15;
    const int quad = (t & 63) >> 4;

    __shared__ unsigned short xsb[64 * 138];   // [pix][c], stride 138 (odd words)
    __shared__ float linv[4][64];

    {
        int h = t >> 6, p = t & 63;
        size_t li = (size_t)(b * 4 + h) * NPIX + n0 + p;
        linv[h][p] = 1.0f / (lbuf[li] + lbuf[li + 65536]);
    }
    __syncthreads();

    const float* a0 = ao + (size_t)(b * CCH) * NPIX + n0;
    const float* a1 = a0 + 2097152;
#pragma unroll
    for (int k = 0; k < 32; ++k) {
        int e = k * 256 + t;
        int c = e >> 6, p = e & 63;
        size_t idx = (size_t)c * NPIX + p;
        xsb[p * 138 + c] = f2bf((a0[idx] + a1[idx]) * linv[c >> 5][p]);
    }
    __syncthreads();

    // A-frags: w_out rows (o = o0 + l16)
    const int o0 = part * 64 + wv * 16;
    const float* wrow = w_out + (size_t)(o0 + l16) * CCH;
    bf8 aw[4];
#pragma unroll
    for (int kk = 0; kk < 4; ++kk) {
        float wb[8];
        *(float4*)&wb[0] = *(const float4*)&wrow[kk * 32 + quad * 8];
        *(float4*)&wb[4] = *(const float4*)&wrow[kk * 32 + quad * 8 + 4];
#pragma unroll
        for (int j = 0; j < 8; ++j) aw[kk][j] = (short)f2bf(wb[j]);
    }

    const f4 z = {0.f, 0.f, 0.f, 0.f};
    f4 acc[4] = {z, z, z, z};
#pragma unroll
    for (int s = 0; s < 4; ++s) {
#pragma unroll
        for (int kk = 0; kk < 4; ++kk) {
            const unsigned short* row = &xsb[(s * 16 + l16) * 138 + kk * 32 + quad * 8];
            union { unsigned u[4]; bf8 v; } pb;
            pb.u[0] = *(const unsigned*)&row[0];
            pb.u[1] = *(const unsigned*)&row[2];
            pb.u[2] = *(const unsigned*)&row[4];
            pb.u[3] = *(const unsigned*)&row[6];
            acc[s] = MFMA(aw[kk], pb.v, acc[s]);
        }
    }

#pragma unroll
    for (int r = 0; r < 4; ++r) {
        const int o = o0 + quad * 4 + r;
        const float bo = b_out[o];
        float* orow = out + (size_t)(b * CCH + o) * NPIX + n0 + l16;
#pragma unroll
        for (int s = 0; s < 4; ++s)
            orow[s * 16] = acc[s][r] + bo;
    }
}

// ---------------------------------------------------------------------------
extern "C" void kernel_launch(void* const* d_in, const int* in_sizes, int n_in,
                              void* d_out, int out_size, void* d_ws, size_t ws_size,
                              hipStream_t stream) {
    const float* x     = (const float*)d_in[0];
    const float* g     = (const float*)d_in[1];
    const float* bvec  = (const float*)d_in[2];
    const float* w_qkv = (const float*)d_in[3];
    const float* w_out = (const float*)d_in[4];
    const float* b_out = (const float*)d_in[5];
    float* out = (float*)d_out;

    char* ws = (char*)d_ws;
    unsigned short* xn   = (unsigned short*)(ws);           // dead after qkv
    float*          lbuf = (float*)(ws);                    // overlays xn, 512 KB
    unsigned short* qh   = (unsigned short*)(ws + (4u  << 20));
    unsigned short* kh   = (unsigned short*)(ws + (8u  << 20));
    unsigned short* vth  = (unsigned short*)(ws + (12u << 20));
    float*          ao   = (float*)(ws + (16u << 20));      // 2 slices x 8MB

    ln_kernel   <<<dim3(512),     dim3(256), 0, stream>>>(x, g, bvec, xn);
    qkv_kernel  <<<dim3(64, 24),  dim3(256), 0, stream>>>(w_qkv, xn, qh, kh, vth);
    flash_kernel<<<dim3(1024),    dim3(256), 0, stream>>>(qh, kh, vth, ao, lbuf);
    proj_kernel <<<dim3(256, 2),  dim3(256), 0, stream>>>(ao, lbuf, w_out, b_out, out);
}

// Round 7
// 186.468 us; speedup vs baseline: 1.6524x; 1.0396x over previous
//
#include <hip/hip_runtime.h>
#include <math.h>

#define NPIX 4096
#define CCH  128

typedef __attribute__((ext_vector_type(8))) short  bf8;   // 8 bf16 in 4 VGPRs
typedef __attribute__((ext_vector_type(4))) float  f4;

#define MFMA(a, b, c) __builtin_amdgcn_mfma_f32_16x16x32_bf16(a, b, c, 0, 0, 0)

__device__ __forceinline__ unsigned short f2bf(float x) {
    union { float f; unsigned u; } v; v.f = x;
    unsigned r = v.u + 0x7fffu + ((v.u >> 16) & 1u);   // RNE
    return (unsigned short)(r >> 16);
}
// pack two floats to bf16x2 (lo in low short), half-ulp RNE, 3 VALU ops
__device__ __forceinline__ unsigned pk2r(float lo, float hi) {
    union { float f; unsigned u; } a, b; a.f = hi; b.f = lo;
    return __builtin_amdgcn_perm(a.u + 0x8000u, b.u + 0x8000u, 0x07060302u);
}
// truncating pack, 1 VALU op. Used ONLY for P in flash: O and l consume the
// same packed P, so the common truncation bias cancels in O/l.
__device__ __forceinline__ unsigned pk2t(float lo, float hi) {
    union { float f; unsigned u; } a, b; a.f = hi; b.f = lo;
    return __builtin_amdgcn_perm(a.u, b.u, 0x07060302u);
}

// Workspace layout (bytes), 32 MB:
//   lbuf 0..512K     fp32 2 slices [bh][n]   (flash out)
//   wqb  1M..1.094M  bf16 [384][128]  (q rows pre-scaled by 32^-.5*log2e)
//   wob  1.5M..1.53M bf16 [128][128]
//   qh   4..8M       bf16 [bh][n][32]
//   kh   8..12M      bf16 [bh][n][32]
//   vth  12..16M     bf16 [bh*32+d][n]
//   ao   16..32M     fp32 2 slices [bh*32+d][n]

// ---------------------------------------------------------------------------
// Kernel 0: convert weights to bf16 (q rows scaled). grid 256 x 256.
// ---------------------------------------------------------------------------
__global__ __launch_bounds__(256) void wconv_kernel(
    const float* __restrict__ wq, const float* __restrict__ wo,
    unsigned short* __restrict__ wqb, unsigned short* __restrict__ wob)
{
    const float qs2 = 0.17677669529663687f * 1.4426950408889634f;
    int i = blockIdx.x * 256 + threadIdx.x;       // 0..65535
    if (i < 49152) {
        float f = wq[i];
        if (i < 16384) f *= qs2;                  // q rows 0..127
        wqb[i] = f2bf(f);
    } else {
        int j = i - 49152;
        wob[j] = f2bf(wo[j]);
    }
}

// ---------------------------------------------------------------------------
// Kernel 1: fused LayerNorm + QKV MFMA GEMM. grid 1024 x 256 (16 px/block).
// xn lives only in LDS; q/k stored directly from C-frag (8 B/lane), v d-major.
// ---------------------------------------------------------------------------
__global__ __launch_bounds__(256) void lnqkv_kernel(
    const float* __restrict__ x, const float* __restrict__ g,
    const float* __restrict__ bvec, const unsigned short* __restrict__ wqb,
    unsigned short* __restrict__ qh, unsigned short* __restrict__ kh,
    unsigned short* __restrict__ vth)
{
    const int blk = blockIdx.x;
    const int b  = blk >> 8;
    const int n0 = (blk & 255) << 4;
    const int t  = threadIdx.x;

    __shared__ float xs[CCH * 17];             // [c][pix], stride 17
    __shared__ float red0[16][16];
    __shared__ float red1[16][16];
    __shared__ float mean_s[16];
    __shared__ float rstd_s[16];
    __shared__ unsigned short xnb[16 * 138];   // bf16 [pix][c], stride 138

    const float* xb = x + (size_t)b * CCH * NPIX + n0;
#pragma unroll
    for (int k = 0; k < 8; ++k) {
        int e = k * 256 + t;
        int c = e >> 4, p = e & 15;
        xs[c * 17 + p] = xb[(size_t)c * NPIX + p];
    }
    __syncthreads();

    {
        int pix = t & 15, cg = t >> 4;
        float s = 0.f, s2 = 0.f;
#pragma unroll
        for (int cc = 0; cc < 8; ++cc) {
            float v = xs[(cg * 8 + cc) * 17 + pix];
            s += v; s2 += v * v;
        }
        red0[cg][pix] = s; red1[cg][pix] = s2;
    }
    __syncthreads();
    if (t < 16) {
        float s = 0.f, s2 = 0.f;
#pragma unroll
        for (int cg = 0; cg < 16; ++cg) { s += red0[cg][t]; s2 += red1[cg][t]; }
        float mu  = s * (1.f / 128.f);
        float var = s2 * (1.f / 128.f) - mu * mu;
        mean_s[t] = mu;
        rstd_s[t] = rsqrtf(var + 1e-5f);
    }
    __syncthreads();

    // normalize + pack into LDS: thread -> (pix = t>>4, c0 = (t&15)*8)
    {
        const int pix = t >> 4;
        const int c0  = (t & 15) * 8;
        const float mu = mean_s[pix], rs = rstd_s[pix];
#pragma unroll
        for (int i = 0; i < 4; ++i) {
            int c = c0 + 2 * i;
            float f0 = (xs[c * 17 + pix]       - mu) * rs * g[c]     + bvec[c];
            float f1 = (xs[(c + 1) * 17 + pix] - mu) * rs * g[c + 1] + bvec[c + 1];
            *(unsigned*)&xnb[pix * 138 + c] = pk2r(f0, f1);
        }
    }
    __syncthreads();

    // MFMA GEMM: wave wv covers o-tiles wv*6 .. wv*6+5 (16 outputs each).
    const int wv   = t >> 6;
    const int l16  = t & 15;
    const int quad = (t & 63) >> 4;

    for (int it = 0; it < 6; ++it) {
        const int ot = wv * 6 + it;          // 0-7 q, 8-15 k, 16-23 v
        const unsigned short* wr = wqb + (size_t)(ot * 16 + l16) * CCH;
        f4 acc = {0.f, 0.f, 0.f, 0.f};
#pragma unroll
        for (int kk = 0; kk < 4; ++kk) {
            const bf8 a = *(const bf8*)&wr[kk * 32 + quad * 8];
            const unsigned short* xr = &xnb[l16 * 138 + kk * 32 + quad * 8];
            union { unsigned u[4]; bf8 v; } bx;
            bx.u[0] = *(const unsigned*)&xr[0];
            bx.u[1] = *(const unsigned*)&xr[2];
            bx.u[2] = *(const unsigned*)&xr[4];
            bx.u[3] = *(const unsigned*)&xr[6];
            acc = MFMA(a, bx.v, acc);
        }
        // C-frag: col(px)=l16, row o = ot*16 + quad*4 + r
        if (ot < 16) {
            // q/k: [n][d] rows; lane writes its 4 d's as 8B (contiguous per quad)
            const int h  = (ot >> 1) & 3;
            const int d0 = (ot & 1) * 16 + quad * 4;
            const int bh = b * 4 + h;
            unsigned short* dst = ((ot < 8) ? qh : kh)
                                + ((size_t)bh * NPIX + n0 + l16) * 32 + d0;
            uint2 wp;
            wp.x = pk2r(acc.x, acc.y);
            wp.y = pk2r(acc.z, acc.w);
            *(uint2*)dst = wp;
        } else {
            // v: d-major [bh*32+d][n]
            const int bh = b * 4 + ((ot - 16) >> 1);
            const int dv = ((ot - 16) & 1) * 16 + quad * 4;
#pragma unroll
            for (int r = 0; r < 4; ++r)
                vth[((size_t)bh * 32 + dv + r) * NPIX + n0 + l16] = f2bf(acc[r]);
        }
    }
}

// ---------------------------------------------------------------------------
// Kernel 2: MFMA flash attention — R6-proven config (split-K 2, fp32 stores,
// 4 blocks/CU), with truncating P-pack. grid 1024, XCD-swizzled.
// ---------------------------------------------------------------------------
struct Frags { bf8 k0, k1, v0, v1; };

__device__ __forceinline__ void loadFrags(Frags& f,
    const unsigned short* __restrict__ khb, const unsigned short* __restrict__ vhb,
    int j0, int l16, int quad)
{
    const size_t ka0 = (size_t)(j0 + l16) * 32 + quad * 8;
    f.k0 = *(const bf8*)&khb[ka0];
    f.k1 = *(const bf8*)&khb[ka0 + 16 * 32];
    const size_t va0 = (size_t)l16 * NPIX + j0 + quad * 8;
    f.v0 = *(const bf8*)&vhb[va0];
    f.v1 = *(const bf8*)&vhb[va0 + (size_t)16 * NPIX];
}

__device__ __forceinline__ void tileCompute(const Frags& f,
    const bf8 qA, const bf8 qB, const bf8 ones,
    f4& o00, f4& o10, f4& o01, f4& o11, f4& lA, f4& lB,
    unsigned short (*pbA)[56], unsigned short (*pbB)[56], int l16, int quad)
{
    const f4 z = {0.f, 0.f, 0.f, 0.f};
    f4 sA0 = MFMA(f.k0, qA, z);
    f4 sA1 = MFMA(f.k1, qA, z);
    f4 sB0 = MFMA(f.k0, qB, z);
    f4 sB1 = MFMA(f.k1, qB, z);

    float pA0 = __builtin_amdgcn_exp2f(sA0.x), pA1 = __builtin_amdgcn_exp2f(sA0.y);
    float pA2 = __builtin_amdgcn_exp2f(sA0.z), pA3 = __builtin_amdgcn_exp2f(sA0.w);
    float pA4 = __builtin_amdgcn_exp2f(sA1.x), pA5 = __builtin_amdgcn_exp2f(sA1.y);
    float pA6 = __builtin_amdgcn_exp2f(sA1.z), pA7 = __builtin_amdgcn_exp2f(sA1.w);
    float pB0 = __builtin_amdgcn_exp2f(sB0.x), pB1 = __builtin_amdgcn_exp2f(sB0.y);
    float pB2 = __builtin_amdgcn_exp2f(sB0.z), pB3 = __builtin_amdgcn_exp2f(sB0.w);
    float pB4 = __builtin_amdgcn_exp2f(sB1.x), pB5 = __builtin_amdgcn_exp2f(sB1.y);
    float pB6 = __builtin_amdgcn_exp2f(sB1.z), pB7 = __builtin_amdgcn_exp2f(sB1.w);

    unsigned* prA = (unsigned*)&pbA[l16][quad * 4];
    prA[0] = pk2t(pA0, pA1); prA[1] = pk2t(pA2, pA3);
    prA[8] = pk2t(pA4, pA5); prA[9] = pk2t(pA6, pA7);
    unsigned* prB = (unsigned*)&pbB[l16][quad * 4];
    prB[0] = pk2t(pB0, pB1); prB[1] = pk2t(pB2, pB3);
    prB[8] = pk2t(pB4, pB5); prB[9] = pk2t(pB6, pB7);

    const bf8 pfA = *(const bf8*)&pbA[l16][quad * 8];
    const bf8 pfB = *(const bf8*)&pbB[l16][quad * 8];

    o00 = MFMA(f.v0, pfA, o00); o10 = MFMA(f.v1, pfA, o10);
    o01 = MFMA(f.v0, pfB, o01); o11 = MFMA(f.v1, pfB, o11);
    lA  = MFMA(ones, pfA, lA);  lB  = MFMA(ones, pfB, lB);
}

__global__ __launch_bounds__(256, 4) void flash_kernel(
    const unsigned short* __restrict__ qh, const unsigned short* __restrict__ kh,
    const unsigned short* __restrict__ vth,
    float* __restrict__ ao, float* __restrict__ lbuf)
{
    const int blk = blockIdx.x;
    const int bh  = (blk & 7) + 8 * ((blk >> 3) & 1);   // XCD-local per bh
    const int rem = blk >> 4;
    const int qt  = rem & 31;
    const int ks  = rem >> 5;                            // 0..1
    const int t   = threadIdx.x;
    const int wv  = t >> 6;
    const int l16 = t & 15;
    const int quad = (t & 63) >> 4;
    const int q0  = qt * 128 + wv * 32;

    __shared__ unsigned short pbuf_raw[4][2][16][56];   // 14 KB
    unsigned short (*pbA)[56] = pbuf_raw[wv][0];
    unsigned short (*pbB)[56] = pbuf_raw[wv][1];

    const size_t qbaseA = ((size_t)bh * NPIX + q0 + l16) * 32 + quad * 8;
    const bf8 qA = *(const bf8*)&qh[qbaseA];
    const bf8 qB = *(const bf8*)&qh[qbaseA + 16 * 32];

    const unsigned short* khb = kh  + (size_t)bh * NPIX * 32;
    const unsigned short* vhb = vth + (size_t)bh * 32 * NPIX;

    const short one = (short)0x3f80;
    const bf8 ones = {one, one, one, one, one, one, one, one};

    const f4 z = {0.f, 0.f, 0.f, 0.f};
    f4 o00 = z, o10 = z, o01 = z, o11 = z, lA = z, lB = z;

    const int jbase = ks * 2048;
    Frags fa, fb;
    loadFrags(fa, khb, vhb, jbase, l16, quad);
    for (int jt = 0; jt < 64; jt += 2) {
        loadFrags(fb, khb, vhb, jbase + (jt + 1) * 32, l16, quad);
        tileCompute(fa, qA, qB, ones, o00, o10, o01, o11, lA, lB, pbA, pbB, l16, quad);
        loadFrags(fa, khb, vhb, jbase + (jt + 2) * 32, l16, quad);  // tail over-read stays in ws
        tileCompute(fb, qA, qB, ones, o00, o10, o01, o11, lA, lB, pbA, pbB, l16, quad);
    }

    // epilogue: fp32 stores, full 128B line coverage per wave (A+B adjacent)
    float* aos = ao + (size_t)ks * 2097152;
    float* lbs = lbuf + (size_t)ks * 65536;
    float* aoA = aos + (size_t)bh * 32 * NPIX + q0 + l16;
    float* aoB = aoA + 16;
#pragma unroll
    for (int r = 0; r < 4; ++r) {
        aoA[(size_t)(quad * 4 + r) * NPIX]      = o00[r];
        aoA[(size_t)(16 + quad * 4 + r) * NPIX] = o10[r];
        aoB[(size_t)(quad * 4 + r) * NPIX]      = o01[r];
        aoB[(size_t)(16 + quad * 4 + r) * NPIX] = o11[r];
    }
    if (quad == 0) {
        lbs[(size_t)bh * NPIX + q0 + l16]      = lA.x;
        lbs[(size_t)bh * NPIX + q0 + 16 + l16] = lB.x;
    }
}

// ---------------------------------------------------------------------------
// Kernel 3: sum 2 fp32 O-slices, normalize, MFMA projection + bias.
// grid (512, 2): block = 32 px, part = 64-output half. bf16 weights.
// ---------------------------------------------------------------------------
__global__ __launch_bounds__(256) void proj_kernel(
    const float* __restrict__ ao, const float* __restrict__ lbuf,
    const unsigned short* __restrict__ wob, const float* __restrict__ b_out,
    float* __restrict__ out)
{
    const int blk  = blockIdx.x;
    const int part = blockIdx.y;
    const int b  = blk >> 7;
    const int n0 = (blk & 127) << 5;
    const int t  = threadIdx.x;
    const int wv = t >> 6;
    const int l16 = t & 15;
    const int quad = (t & 63) >> 4;

    __shared__ unsigned short xsb[32 * 138];   // [pix][c], stride 138
    __shared__ float linv[4][32];

    if (t < 128) {
        int h = t >> 5, p = t & 31;
        size_t li = (size_t)(b * 4 + h) * NPIX + n0 + p;
        linv[h][p] = 1.0f / (lbuf[li] + lbuf[li + 65536]);
    }
    __syncthreads();

    const float* a0 = ao + (size_t)(b * CCH) * NPIX + n0;
    const float* a1 = a0 + 2097152;
#pragma unroll
    for (int k = 0; k < 16; ++k) {
        int e = k * 256 + t;
        int c = e >> 5, p = e & 31;
        size_t idx = (size_t)c * NPIX + p;
        xsb[p * 138 + c] = f2bf((a0[idx] + a1[idx]) * linv[c >> 5][p]);
    }
    __syncthreads();

    // A-frags: wob rows (o = o0 + l16), bf16 direct
    const int o0 = part * 64 + wv * 16;
    const unsigned short* wrow = wob + (size_t)(o0 + l16) * CCH;
    bf8 aw[4];
#pragma unroll
    for (int kk = 0; kk < 4; ++kk)
        aw[kk] = *(const bf8*)&wrow[kk * 32 + quad * 8];

    const f4 z = {0.f, 0.f, 0.f, 0.f};
    f4 acc[2] = {z, z};
#pragma unroll
    for (int s = 0; s < 2; ++s) {
#pragma unroll
        for (int kk = 0; kk < 4; ++kk) {
            const unsigned short* row = &xsb[(s * 16 + l16) * 138 + kk * 32 + quad * 8];
            union { unsigned u[4]; bf8 v; } pb;
            pb.u[0] = *(const unsigned*)&row[0];
            pb.u[1] = *(const unsigned*)&row[2];
            pb.u[2] = *(const unsigned*)&row[4];
            pb.u[3] = *(const unsigned*)&row[6];
            acc[s] = MFMA(aw[kk], pb.v, acc[s]);
        }
    }

#pragma unroll
    for (int r = 0; r < 4; ++r) {
        const int o = o0 + quad * 4 + r;
        const float bo = b_out[o];
        float* orow = out + (size_t)(b * CCH + o) * NPIX + n0 + l16;
#pragma unroll
        for (int s = 0; s < 2; ++s)
            orow[s * 16] = acc[s][r] + bo;
    }
}

// ---------------------------------------------------------------------------
extern "C" void kernel_launch(void* const* d_in, const int* in_sizes, int n_in,
                              void* d_out, int out_size, void* d_ws, size_t ws_size,
                              hipStream_t stream) {
    const float* x     = (const float*)d_in[0];
    const float* g     = (const float*)d_in[1];
    const float* bvec  = (const float*)d_in[2];
    const float* w_qkv = (const float*)d_in[3];
    const float* w_out = (const float*)d_in[4];
    const float* b_out = (const float*)d_in[5];
    float* out = (float*)d_out;

    char* ws = (char*)d_ws;
    float*          lbuf = (float*)(ws);                      // 0..512K
    unsigned short* wqb  = (unsigned short*)(ws + (1u << 20));
    unsigned short* wob  = (unsigned short*)(ws + (3u << 19)); // 1.5M
    unsigned short* qh   = (unsigned short*)(ws + (4u  << 20));
    unsigned short* kh   = (unsigned short*)(ws + (8u  << 20));
    unsigned short* vth  = (unsigned short*)(ws + (12u << 20));
    float*          ao   = (float*)(ws + (16u << 20));        // 2 slices x 8MB

    wconv_kernel<<<dim3(256),    dim3(256), 0, stream>>>(w_qkv, w_out, wqb, wob);
    lnqkv_kernel<<<dim3(1024),   dim3(256), 0, stream>>>(x, g, bvec, wqb, qh, kh, vth);
    flash_kernel<<<dim3(1024),   dim3(256), 0, stream>>>(qh, kh, vth, ao, lbuf);
    proj_kernel <<<dim3(512, 2), dim3(256), 0, stream>>>(ao, lbuf, wob, b_out, out);
}